// Round 1
// baseline (5205.136 us; speedup 1.0000x reference)
//
#include <hip/hip_runtime.h>

#define BS 16
#define LQ 300
#define D 256
#define NH 8
#define HD 32
#define DFF 1024
#define ROWS (BS*LQ)    // 4800
#define LEN_V 8500

// ---------------------------------------------------------------------------
// Generic f32 GEMM: C[m, coff+n] = act( sum_k A[m,k] * W[n,k] + bias[n] )
// A: [M, lda] row-major, W: [N, K] row-major. Tiles 64x64, BK=16, 256 thr.
// All M,N,K used here divide the tile sizes exactly (M=4800, N%64==0, K%16==0).
// ACT: 0=none, 1=relu, 2=sigmoid
// ---------------------------------------------------------------------------
template<int ACT>
__global__ __launch_bounds__(256)
void gemm_tn(const float* __restrict__ A, int lda,
             const float* __restrict__ W,
             const float* __restrict__ bias,
             float* __restrict__ C, int ldc, int coff,
             int K)
{
    // K-major LDS with +4 pad: compute reads are 16B-aligned ds_read_b128,
    // conflict-free (A broadcast, B 2-way which is free on CDNA4).
    __shared__ float As[16][68];
    __shared__ float Bs[16][68];
    const int tid = threadIdx.x;
    const int bm = blockIdx.x, bn = blockIdx.y;
    const int tx = tid & 15, ty = tid >> 4;
    const int r   = tid >> 2;         // 0..63 staging row
    const int kk4 = (tid & 3) << 2;   // 0,4,8,12

    const float* Ab = A + (size_t)(bm*64 + r)*lda + kk4;
    const float* Wb = W + (size_t)(bn*64 + r)*K   + kk4;

    float acc[4][4] = {};
    for (int k0 = 0; k0 < K; k0 += 16) {
        const float4 av = *reinterpret_cast<const float4*>(Ab + k0);
        const float4 bv = *reinterpret_cast<const float4*>(Wb + k0);
        __syncthreads();
        As[kk4+0][r] = av.x; As[kk4+1][r] = av.y; As[kk4+2][r] = av.z; As[kk4+3][r] = av.w;
        Bs[kk4+0][r] = bv.x; Bs[kk4+1][r] = bv.y; Bs[kk4+2][r] = bv.z; Bs[kk4+3][r] = bv.w;
        __syncthreads();
#pragma unroll
        for (int kk = 0; kk < 16; ++kk) {
            const float4 a4 = *reinterpret_cast<const float4*>(&As[kk][ty << 2]);
            const float4 b4 = *reinterpret_cast<const float4*>(&Bs[kk][tx << 2]);
            const float aa[4] = {a4.x, a4.y, a4.z, a4.w};
            const float bb[4] = {b4.x, b4.y, b4.z, b4.w};
#pragma unroll
            for (int i = 0; i < 4; ++i)
#pragma unroll
                for (int j = 0; j < 4; ++j)
                    acc[i][j] += aa[i] * bb[j];
        }
    }
    const int row = (bm << 6) + (ty << 2);
    const int col = (bn << 6) + (tx << 2);
#pragma unroll
    for (int i = 0; i < 4; ++i)
#pragma unroll
        for (int j = 0; j < 4; ++j) {
            float v = acc[i][j] + bias[col + j];
            if (ACT == 1) v = fmaxf(v, 0.f);
            if (ACT == 2) v = 1.f / (1.f + __expf(-v));
            C[(size_t)(row + i)*ldc + coff + col + j] = v;
        }
}

// ---------------------------------------------------------------------------
// q = t + pos
// ---------------------------------------------------------------------------
__global__ __launch_bounds__(256)
void add_pos(const float* __restrict__ t, const float* __restrict__ pos,
             float* __restrict__ q)
{
    const size_t idx = (size_t)blockIdx.x*256 + threadIdx.x;
    q[idx] = t[idx] + pos[idx];
}

// ---------------------------------------------------------------------------
// Fused MHA: one wave per (b,h,iq). qkv layout [b][row][768] (q|k|v).
// ---------------------------------------------------------------------------
__global__ __launch_bounds__(64)
void mha_fused(const float* __restrict__ qkv, float* __restrict__ o)
{
    const int bh = blockIdx.x / LQ;        // b*8 + h
    const int iq = blockIdx.x % LQ;
    const int b  = bh >> 3, h = bh & 7;
    const int lane = threadIdx.x;
    const int d  = lane & 31;
    const int jj = lane >> 5;              // 0 or 1
    __shared__ float qs[32];
    __shared__ float sc[LQ];
    const float* base = qkv + (size_t)b * LQ * 768;
    const int hc = h * 32;
    if (lane < 32) qs[lane] = base[(size_t)iq*768 + hc + lane];
    __syncthreads();
    const float scale = 0.17677669529663687f;   // 1/sqrt(32)
    // scores: 2 keys per iteration (one per 32-lane half), lane d holds dim d
    for (int j0 = 0; j0 < LQ; j0 += 2) {
        const int j = j0 + jj;
        float p = base[(size_t)j*768 + 256 + hc + d] * qs[d];
#pragma unroll
        for (int off = 16; off; off >>= 1) p += __shfl_down(p, off, 32);
        if (d == 0) sc[j] = p * scale;
    }
    __syncthreads();
    // softmax over sc[0..299]
    float m = -1e30f;
    for (int j = lane; j < LQ; j += 64) m = fmaxf(m, sc[j]);
#pragma unroll
    for (int off = 32; off; off >>= 1) m = fmaxf(m, __shfl_xor(m, off, 64));
    float s = 0.f;
    for (int j = lane; j < LQ; j += 64) { const float e = __expf(sc[j]-m); sc[j] = e; s += e; }
#pragma unroll
    for (int off = 32; off; off >>= 1) s += __shfl_xor(s, off, 64);
    const float inv = 1.f / s;
    __syncthreads();
    // PV: each 32-lane half handles alternate keys, then combine
    float acc = 0.f;
    for (int j = jj; j < LQ; j += 2)
        acc += sc[j] * base[(size_t)j*768 + 512 + hc + d];
    acc += __shfl_down(acc, 32, 64);
    if (lane < 32)
        o[((size_t)(b*LQ + iq))*256 + hc + d] = acc * inv;
}

// ---------------------------------------------------------------------------
// block-of-256 row reduction helper (4 waves)
// ---------------------------------------------------------------------------
__device__ __forceinline__ float blk_sum(float v, float* red)
{
#pragma unroll
    for (int off = 32; off; off >>= 1) v += __shfl_down(v, off, 64);
    const int lane = threadIdx.x & 63, w = threadIdx.x >> 6;
    if (lane == 0) red[w] = v;
    __syncthreads();
    const float s = red[0] + red[1] + red[2] + red[3];
    __syncthreads();
    return s;
}

// t_out = LN(t + t2)*g + b ; q_out = t_out + pos
__global__ __launch_bounds__(256)
void ln_res_pos(const float* __restrict__ t, const float* __restrict__ t2,
                const float* __restrict__ g, const float* __restrict__ bb,
                const float* __restrict__ pos,
                float* __restrict__ t_out, float* __restrict__ q_out)
{
    __shared__ float red[4];
    const size_t idx = (size_t)blockIdx.x*256 + threadIdx.x;
    const float x = t[idx] + t2[idx];
    const float mean = blk_sum(x, red) * (1.f/256.f);
    const float c = x - mean;
    const float var = blk_sum(c*c, red) * (1.f/256.f);
    const float y = c * rsqrtf(var + 1e-5f) * g[threadIdx.x] + bb[threadIdx.x];
    t_out[idx] = y;
    q_out[idx] = y + pos[idx];
}

// t_out = LN(g1*t + g2*t2)*g + b   (g1,g2 = sigmoid gates, already applied in GEMM)
__global__ __launch_bounds__(256)
void gate_ln(const float* __restrict__ t, const float* __restrict__ t2,
             const float* __restrict__ gates,
             const float* __restrict__ g, const float* __restrict__ bb,
             float* __restrict__ t_out)
{
    __shared__ float red[4];
    const int row = blockIdx.x, dd = threadIdx.x;
    const size_t idx = (size_t)row*256 + dd;
    const float g1 = gates[(size_t)row*512 + dd];
    const float g2 = gates[(size_t)row*512 + 256 + dd];
    const float x = g1 * t[idx] + g2 * t2[idx];
    const float mean = blk_sum(x, red) * (1.f/256.f);
    const float c = x - mean;
    const float var = blk_sum(c*c, red) * (1.f/256.f);
    t_out[idx] = c * rsqrtf(var + 1e-5f) * g[dd] + bb[dd];
}

// out = LN(clip(t + t2))*g + b
__global__ __launch_bounds__(256)
void ln_clip(const float* __restrict__ t, const float* __restrict__ t2,
             const float* __restrict__ g, const float* __restrict__ bb,
             float* __restrict__ outp)
{
    __shared__ float red[4];
    const size_t idx = (size_t)blockIdx.x*256 + threadIdx.x;
    float x = t[idx] + t2[idx];
    x = fminf(fmaxf(x, -65504.f), 65504.f);
    const float mean = blk_sum(x, red) * (1.f/256.f);
    const float c = x - mean;
    const float var = blk_sum(c*c, red) * (1.f/256.f);
    outp[idx] = c * rsqrtf(var + 1e-5f) * g[threadIdx.x] + bb[threadIdx.x];
}

// ---------------------------------------------------------------------------
// softmax over the 16 sampling points per (b,q,h); aw layout [bq][128]=[h][p]
// ---------------------------------------------------------------------------
__global__ __launch_bounds__(128)
void aw_softmax(float* __restrict__ aw)
{
    const int bq = blockIdx.x;
    const int tid = threadIdx.x;
    const float v = aw[(size_t)bq*128 + tid];
    float m = v;
#pragma unroll
    for (int off = 8; off; off >>= 1) m = fmaxf(m, __shfl_xor(m, off, 16));
    const float e = __expf(v - m);
    float s = e;
#pragma unroll
    for (int off = 8; off; off >>= 1) s += __shfl_xor(s, off, 16);
    aw[(size_t)bq*128 + tid] = e / s;
}

// ---------------------------------------------------------------------------
// MS-deformable attention gather. One block per (b,q); 256 thr = 8 heads x 32 d.
// Threads 0..127 precompute the 4 corner (row,weight) pairs per (h,p) into LDS.
// ---------------------------------------------------------------------------
__global__ __launch_bounds__(256)
void deform_attn(const float* __restrict__ value, const float* __restrict__ refp,
                 const float* __restrict__ so, const float* __restrict__ aw,
                 float* __restrict__ outp)
{
    const int bq = blockIdx.x;
    const int b  = bq / LQ;
    const int tid = threadIdx.x;
    __shared__ int   s_idx[128][4];
    __shared__ float s_w[128][4];
    if (tid < 128) {
        const int hp = tid;
        const int p  = hp & 15;
        const int lvl = p >> 2;
        const float Wl = (lvl == 0) ? 80.f : (lvl == 1) ? 40.f : (lvl == 2) ? 20.f : 10.f;
        const float Hl = Wl;
        const int off  = (lvl == 0) ? 0 : (lvl == 1) ? 6400 : (lvl == 2) ? 8000 : 8400;
        const float cx = refp[bq*4+0], cy = refp[bq*4+1];
        const float rw = refp[bq*4+2], rh = refp[bq*4+3];
        // loc = ref.xy + so * (1/NPTS) * ref.wh * OFFSET_SCALE  -> * 0.125
        const float lx = cx + so[(size_t)bq*256 + hp*2 + 0] * rw * 0.125f;
        const float ly = cy + so[(size_t)bq*256 + hp*2 + 1] * rh * 0.125f;
        const float x = lx * Wl - 0.5f;
        const float y = ly * Hl - 0.5f;
        const float x0 = floorf(x), y0 = floorf(y);
        const float wx1 = x - x0, wx0 = 1.f - wx1;
        const float wy1 = y - y0, wy0 = 1.f - wy1;
        const float a = aw[(size_t)bq*128 + hp];
        const float xs[2]  = {x0, x0 + 1.f}, ys[2]  = {y0, y0 + 1.f};
        const float wxs[2] = {wx0, wx1},     wys[2] = {wy0, wy1};
#pragma unroll
        for (int cyi = 0; cyi < 2; ++cyi)
#pragma unroll
            for (int cxi = 0; cxi < 2; ++cxi) {
                const float xi = xs[cxi], yi = ys[cyi];
                const bool valid = (xi >= 0.f) && (xi <= Wl - 1.f) &&
                                   (yi >= 0.f) && (yi <= Hl - 1.f);
                const float xc = fminf(fmaxf(xi, 0.f), Wl - 1.f);
                const float yc = fminf(fmaxf(yi, 0.f), Hl - 1.f);
                const int c = cyi*2 + cxi;
                s_idx[hp][c] = (int)(yc*Wl + xc) + off;
                s_w[hp][c]   = valid ? (wxs[cxi]*wys[cyi]*a) : 0.f;
            }
    }
    __syncthreads();
    const int h = tid >> 5, d = tid & 31;
    const int col = h*32 + d;
    const float* vb = value + (size_t)b * LEN_V * 256;
    float acc = 0.f;
#pragma unroll
    for (int p = 0; p < 16; ++p) {
        const int hp = (h << 4) | p;
#pragma unroll
        for (int c = 0; c < 4; ++c)
            acc += s_w[hp][c] * vb[(size_t)s_idx[hp][c]*256 + col];
    }
    outp[(size_t)bq*256 + col] = acc;
}

// cat = [t | t2] per row
__global__ __launch_bounds__(512)
void cat2(const float* __restrict__ t, const float* __restrict__ t2,
          float* __restrict__ catb)
{
    const int row = blockIdx.x, dd = threadIdx.x;
    catb[(size_t)row*512 + dd] = (dd < 256) ? t[(size_t)row*256 + dd]
                                            : t2[(size_t)row*256 + dd - 256];
}

// ---------------------------------------------------------------------------
extern "C" void kernel_launch(void* const* d_in, const int* in_sizes, int n_in,
                              void* d_out, int out_size, void* d_ws, size_t ws_size,
                              hipStream_t stream)
{
    (void)in_sizes; (void)n_in; (void)out_size; (void)ws_size;
    const float* target = (const float*)d_in[0];
    const float* refp   = (const float*)d_in[1];
    const float* value  = (const float*)d_in[2];
    const float* qpos   = (const float*)d_in[3];
    const float* Wqkv   = (const float*)d_in[4];
    const float* bqkv   = (const float*)d_in[5];
    const float* Wo     = (const float*)d_in[6];
    const float* bo     = (const float*)d_in[7];
    const float* n1g    = (const float*)d_in[8];
    const float* n1b    = (const float*)d_in[9];
    const float* soW    = (const float*)d_in[10];
    const float* sob    = (const float*)d_in[11];
    const float* awW    = (const float*)d_in[12];
    const float* awb    = (const float*)d_in[13];
    const float* gW     = (const float*)d_in[14];
    const float* gb     = (const float*)d_in[15];
    const float* gng    = (const float*)d_in[16];
    const float* gnb    = (const float*)d_in[17];
    const float* l1W    = (const float*)d_in[18];
    const float* l1b    = (const float*)d_in[19];
    const float* l2W    = (const float*)d_in[20];
    const float* l2b    = (const float*)d_in[21];
    const float* n3g    = (const float*)d_in[22];
    const float* n3b    = (const float*)d_in[23];

    float* p = (float*)d_ws;
    float* t_buf = p;  p += (size_t)ROWS*D;
    float* q_buf = p;  p += (size_t)ROWS*D;
    float* qkv   = p;                               // ROWS*768
    float* o_buf = qkv + (size_t)ROWS*768;          // ROWS*256
    float* hid   = qkv;                             // aliases qkv+o (ROWS*1024)
    p += (size_t)ROWS*(768 + 256);
    float* t2    = p;  p += (size_t)ROWS*D;
    float* so_b  = p;  p += (size_t)ROWS*D;
    float* aw_b  = p;  p += (size_t)ROWS*128;
    float* cat_b = p;  p += (size_t)ROWS*512;
    float* gates = p;  p += (size_t)ROWS*512;

    hipMemcpyAsync(t_buf, target, (size_t)ROWS*D*sizeof(float),
                   hipMemcpyDeviceToDevice, stream);

    for (int i = 0; i < 6; ++i) {
        const float* Wqkv_i = Wqkv + (size_t)i*768*256;
        const float* bqkv_i = bqkv + (size_t)i*768;
        const float* Wo_i   = Wo   + (size_t)i*256*256;
        const float* bo_i   = bo   + (size_t)i*256;
        const float* n1g_i  = n1g  + (size_t)i*256;
        const float* n1b_i  = n1b  + (size_t)i*256;
        const float* soW_i  = soW  + (size_t)i*256*256;
        const float* sob_i  = sob  + (size_t)i*256;
        const float* awW_i  = awW  + (size_t)i*128*256;
        const float* awb_i  = awb  + (size_t)i*128;
        const float* gW_i   = gW   + (size_t)i*512*512;
        const float* gb_i   = gb   + (size_t)i*512;
        const float* gng_i  = gng  + (size_t)i*256;
        const float* gnb_i  = gnb  + (size_t)i*256;
        const float* l1W_i  = l1W  + (size_t)i*1024*256;
        const float* l1b_i  = l1b  + (size_t)i*1024;
        const float* l2W_i  = l2W  + (size_t)i*256*1024;
        const float* l2b_i  = l2b  + (size_t)i*256;
        const float* n3g_i  = n3g  + (size_t)i*256;
        const float* n3b_i  = n3b  + (size_t)i*256;

        // ---- MHA ----
        add_pos<<<ROWS, 256, 0, stream>>>(t_buf, qpos, q_buf);
        gemm_tn<0><<<dim3(75, 8), 256, 0, stream>>>(q_buf, 256, Wqkv_i,          bqkv_i,       qkv, 768, 0,   256);
        gemm_tn<0><<<dim3(75, 4), 256, 0, stream>>>(t_buf, 256, Wqkv_i + 512*256, bqkv_i + 512, qkv, 768, 512, 256);
        mha_fused<<<BS*NH*LQ, 64, 0, stream>>>(qkv, o_buf);
        gemm_tn<0><<<dim3(75, 4), 256, 0, stream>>>(o_buf, 256, Wo_i, bo_i, t2, 256, 0, 256);
        ln_res_pos<<<ROWS, 256, 0, stream>>>(t_buf, t2, n1g_i, n1b_i, qpos, t_buf, q_buf);

        // ---- deformable attention ----
        gemm_tn<0><<<dim3(75, 4), 256, 0, stream>>>(q_buf, 256, soW_i, sob_i, so_b, 256, 0, 256);
        gemm_tn<0><<<dim3(75, 2), 256, 0, stream>>>(q_buf, 256, awW_i, awb_i, aw_b, 128, 0, 256);
        aw_softmax<<<ROWS, 128, 0, stream>>>(aw_b);
        deform_attn<<<ROWS, 256, 0, stream>>>(value, refp, so_b, aw_b, t2);

        // ---- gating ----
        cat2<<<ROWS, 512, 0, stream>>>(t_buf, t2, cat_b);
        gemm_tn<2><<<dim3(75, 8), 256, 0, stream>>>(cat_b, 512, gW_i, gb_i, gates, 512, 0, 512);
        gate_ln<<<ROWS, 256, 0, stream>>>(t_buf, t2, gates, gng_i, gnb_i, t_buf);

        // ---- FFN ----
        gemm_tn<1><<<dim3(75, 16), 256, 0, stream>>>(t_buf, 256, l1W_i, l1b_i, hid, 1024, 0, 256);
        gemm_tn<0><<<dim3(75, 4), 256, 0, stream>>>(hid, 1024, l2W_i, l2b_i, t2, 256, 0, 1024);
        ln_clip<<<ROWS, 256, 0, stream>>>(t_buf, t2, n3g_i, n3b_i,
                                          (i == 5) ? (float*)d_out : t_buf);
    }
}

// Round 2
// 2350.365 us; speedup vs baseline: 2.2146x; 2.2146x over previous
//
#include <hip/hip_runtime.h>

#define BS 16
#define LQ 300
#define D 256
#define NH 8
#define HD 32
#define DFF 1024
#define ROWS (BS*LQ)    // 4800
#define LEN_V 8500

// ---------------------------------------------------------------------------
// Generic f32 GEMM: C[m, coff+n] = act( sum_k A[m,k] * W[n,k] + bias[n] )
// A: [M, lda] row-major, W: [N, K] row-major. Tiles 64x64, BK=16, 256 thr.
// ACT: 0=none, 1=relu, 2=sigmoid
// ---------------------------------------------------------------------------
template<int ACT>
__global__ __launch_bounds__(256)
void gemm_tn(const float* __restrict__ A, int lda,
             const float* __restrict__ W,
             const float* __restrict__ bias,
             float* __restrict__ C, int ldc, int coff,
             int K)
{
    __shared__ float As[16][68];
    __shared__ float Bs[16][68];
    const int tid = threadIdx.x;
    const int bm = blockIdx.x, bn = blockIdx.y;
    const int tx = tid & 15, ty = tid >> 4;
    const int r   = tid >> 2;         // 0..63 staging row
    const int kk4 = (tid & 3) << 2;   // 0,4,8,12

    const float* Ab = A + (size_t)(bm*64 + r)*lda + kk4;
    const float* Wb = W + (size_t)(bn*64 + r)*K   + kk4;

    float acc[4][4] = {};
    for (int k0 = 0; k0 < K; k0 += 16) {
        const float4 av = *reinterpret_cast<const float4*>(Ab + k0);
        const float4 bv = *reinterpret_cast<const float4*>(Wb + k0);
        __syncthreads();
        As[kk4+0][r] = av.x; As[kk4+1][r] = av.y; As[kk4+2][r] = av.z; As[kk4+3][r] = av.w;
        Bs[kk4+0][r] = bv.x; Bs[kk4+1][r] = bv.y; Bs[kk4+2][r] = bv.z; Bs[kk4+3][r] = bv.w;
        __syncthreads();
#pragma unroll
        for (int kk = 0; kk < 16; ++kk) {
            const float4 a4 = *reinterpret_cast<const float4*>(&As[kk][ty << 2]);
            const float4 b4 = *reinterpret_cast<const float4*>(&Bs[kk][tx << 2]);
            const float aa[4] = {a4.x, a4.y, a4.z, a4.w};
            const float bb[4] = {b4.x, b4.y, b4.z, b4.w};
#pragma unroll
            for (int i = 0; i < 4; ++i)
#pragma unroll
                for (int j = 0; j < 4; ++j)
                    acc[i][j] += aa[i] * bb[j];
        }
    }
    const int row = (bm << 6) + (ty << 2);
    const int col = (bn << 6) + (tx << 2);
#pragma unroll
    for (int i = 0; i < 4; ++i)
#pragma unroll
        for (int j = 0; j < 4; ++j) {
            float v = acc[i][j] + bias[col + j];
            if (ACT == 1) v = fmaxf(v, 0.f);
            if (ACT == 2) v = 1.f / (1.f + __expf(-v));
            C[(size_t)(row + i)*ldc + coff + col + j] = v;
        }
}

// ---------------------------------------------------------------------------
__global__ __launch_bounds__(256)
void add_pos(const float* __restrict__ t, const float* __restrict__ pos,
             float* __restrict__ q)
{
    const size_t idx = (size_t)blockIdx.x*256 + threadIdx.x;
    q[idx] = t[idx] + pos[idx];
}

// ---------------------------------------------------------------------------
// bf16 round-to-nearest-even helper (returns low 16 bits)
// ---------------------------------------------------------------------------
__device__ __forceinline__ uint32_t bf16r(float x)
{
    const uint32_t u = __float_as_uint(x);
    return (u + 0x7fffu + ((u >> 16) & 1u)) >> 16;
}
__device__ __forceinline__ float lof(uint32_t p) { return __uint_as_float(p << 16); }
__device__ __forceinline__ float hif(uint32_t p) { return __uint_as_float(p & 0xffff0000u); }

// ---------------------------------------------------------------------------
// Fused MHA, keys-across-lanes. One block per (b, h, quarter-of-queries).
// 256 threads = 4 waves; each wave owns ~19 queries. K/V staged in LDS as
// packed bf16x2 (K over d-pairs, V over key-pairs). No per-score shuffle
// chains: lane l scores keys l, 64+l, ..., softmax via 6 wave-wide shfl_xor.
// qkv layout [b][row][768] (q|k|v).
// ---------------------------------------------------------------------------
__global__ __launch_bounds__(256)
void mha_block(const float* __restrict__ qkv, float* __restrict__ o)
{
    const int blk = blockIdx.x;          // ((b*8+h)*4 + quarter)
    const int quarter = blk & 3;
    const int bh = blk >> 2;
    const int b = bh >> 3, h = bh & 7;
    const int tid = threadIdx.x;
    const int lane = tid & 63;
    const int w = tid >> 6;

    __shared__ uint32_t Kp[16][320];     // [d-pair][key], pad cols 300..319 = 0
    __shared__ uint32_t Vp[150][32];     // [key-pair][d]
    __shared__ float    ws[4][304];      // per-wave softmax weights
    const float* base = qkv + (size_t)b * LQ * 768;
    const int hc = h * 32;

    // stage K packed over d-pairs: Kp[d2][j] = (bf16(K[j][2d2+1])<<16) | bf16(K[j][2d2])
    for (int idx = tid; idx < 300*16; idx += 256) {
        const int j = idx >> 4, d2 = idx & 15;
        const float2 kv = *reinterpret_cast<const float2*>(base + (size_t)j*768 + 256 + hc + 2*d2);
        Kp[d2][j] = (bf16r(kv.y) << 16) | bf16r(kv.x);
    }
    for (int idx = tid; idx < 16*20; idx += 256)      // zero the tail pad
        Kp[idx/20][300 + idx%20] = 0;
    // stage V packed over key-pairs: Vp[jp][d] = (bf16(V[2jp+1][d])<<16)|bf16(V[2jp][d])
    for (int idx = tid; idx < 150*32; idx += 256) {
        const int jp = idx >> 5, d = idx & 31;
        const float lo = base[(size_t)(2*jp  )*768 + 512 + hc + d];
        const float hi = base[(size_t)(2*jp+1)*768 + 512 + hc + d];
        Vp[jp][d] = (bf16r(hi) << 16) | bf16r(lo);
    }
    __syncthreads();

    const float scale = 0.17677669529663687f;   // 1/sqrt(32)
    const int qbase = quarter * 75;
    for (int il = w; il < 75; il += 4) {
        const int iq = qbase + il;
        const float2* qrow = reinterpret_cast<const float2*>(base + (size_t)iq*768 + hc);

        // ---- scores: lane handles keys lane, 64+lane, ..., 256+lane ----
        float s0=0.f, s1=0.f, s2=0.f, s3=0.f, s4=0.f;
#pragma unroll
        for (int d2 = 0; d2 < 16; ++d2) {
            const float2 q2 = qrow[d2];          // broadcast (same addr all lanes)
            uint32_t k;
            k = Kp[d2][lane      ]; s0 += lof(k)*q2.x + hif(k)*q2.y;
            k = Kp[d2][lane +  64]; s1 += lof(k)*q2.x + hif(k)*q2.y;
            k = Kp[d2][lane + 128]; s2 += lof(k)*q2.x + hif(k)*q2.y;
            k = Kp[d2][lane + 192]; s3 += lof(k)*q2.x + hif(k)*q2.y;
            k = Kp[d2][lane + 256]; s4 += lof(k)*q2.x + hif(k)*q2.y;
        }
        s0 *= scale; s1 *= scale; s2 *= scale; s3 *= scale;
        s4 = (lane < 44) ? s4*scale : -3e38f;     // keys 256+lane valid iff lane<44

        // ---- softmax over 300 keys (wave-wide) ----
        float m = fmaxf(fmaxf(fmaxf(s0,s1), fmaxf(s2,s3)), s4);
#pragma unroll
        for (int off = 32; off; off >>= 1) m = fmaxf(m, __shfl_xor(m, off));
        const float e0 = __expf(s0-m), e1 = __expf(s1-m), e2 = __expf(s2-m), e3 = __expf(s3-m);
        const float e4 = (lane < 44) ? __expf(s4-m) : 0.f;
        float sum = e0+e1+e2+e3+e4;
#pragma unroll
        for (int off = 32; off; off >>= 1) sum += __shfl_xor(sum, off);
        const float inv = 1.f / sum;
        ws[w][lane      ] = e0;
        ws[w][lane +  64] = e1;
        ws[w][lane + 128] = e2;
        ws[w][lane + 192] = e3;
        if (lane < 44) ws[w][lane + 256] = e4;

        // ---- PV: halves split the 150 key-pairs; lane d accumulates out[d] ----
        const int half = lane >> 5, d = lane & 31;
        float acc = 0.f;
#pragma unroll 5
        for (int jp = half*75; jp < half*75 + 75; ++jp) {
            const float2 w2 = *reinterpret_cast<const float2*>(&ws[w][2*jp]);
            const uint32_t v2 = Vp[jp][d];
            acc += lof(v2)*w2.x + hif(v2)*w2.y;
        }
        acc += __shfl_down(acc, 32);
        if (lane < 32)
            o[((size_t)(b*LQ + iq))*256 + hc + d] = acc * inv;
    }
}

// ---------------------------------------------------------------------------
// block-of-256 row reduction helper (4 waves)
// ---------------------------------------------------------------------------
__device__ __forceinline__ float blk_sum(float v, float* red)
{
#pragma unroll
    for (int off = 32; off; off >>= 1) v += __shfl_down(v, off, 64);
    const int lane = threadIdx.x & 63, w = threadIdx.x >> 6;
    if (lane == 0) red[w] = v;
    __syncthreads();
    const float s = red[0] + red[1] + red[2] + red[3];
    __syncthreads();
    return s;
}

// t_out = LN(t + t2)*g + b ; q_out = t_out + pos
__global__ __launch_bounds__(256)
void ln_res_pos(const float* __restrict__ t, const float* __restrict__ t2,
                const float* __restrict__ g, const float* __restrict__ bb,
                const float* __restrict__ pos,
                float* __restrict__ t_out, float* __restrict__ q_out)
{
    __shared__ float red[4];
    const size_t idx = (size_t)blockIdx.x*256 + threadIdx.x;
    const float x = t[idx] + t2[idx];
    const float mean = blk_sum(x, red) * (1.f/256.f);
    const float c = x - mean;
    const float var = blk_sum(c*c, red) * (1.f/256.f);
    const float y = c * rsqrtf(var + 1e-5f) * g[threadIdx.x] + bb[threadIdx.x];
    t_out[idx] = y;
    q_out[idx] = y + pos[idx];
}

// t_out = LN(g1*t + g2*t2)*g + b
__global__ __launch_bounds__(256)
void gate_ln(const float* __restrict__ t, const float* __restrict__ t2,
             const float* __restrict__ gates,
             const float* __restrict__ g, const float* __restrict__ bb,
             float* __restrict__ t_out)
{
    __shared__ float red[4];
    const int row = blockIdx.x, dd = threadIdx.x;
    const size_t idx = (size_t)row*256 + dd;
    const float g1 = gates[(size_t)row*512 + dd];
    const float g2 = gates[(size_t)row*512 + 256 + dd];
    const float x = g1 * t[idx] + g2 * t2[idx];
    const float mean = blk_sum(x, red) * (1.f/256.f);
    const float c = x - mean;
    const float var = blk_sum(c*c, red) * (1.f/256.f);
    t_out[idx] = c * rsqrtf(var + 1e-5f) * g[dd] + bb[dd];
}

// out = LN(clip(t + t2))*g + b
__global__ __launch_bounds__(256)
void ln_clip(const float* __restrict__ t, const float* __restrict__ t2,
             const float* __restrict__ g, const float* __restrict__ bb,
             float* __restrict__ outp)
{
    __shared__ float red[4];
    const size_t idx = (size_t)blockIdx.x*256 + threadIdx.x;
    float x = t[idx] + t2[idx];
    x = fminf(fmaxf(x, -65504.f), 65504.f);
    const float mean = blk_sum(x, red) * (1.f/256.f);
    const float c = x - mean;
    const float var = blk_sum(c*c, red) * (1.f/256.f);
    outp[idx] = c * rsqrtf(var + 1e-5f) * g[threadIdx.x] + bb[threadIdx.x];
}

// ---------------------------------------------------------------------------
// softmax over the 16 sampling points per (b,q,h); aw layout [bq][128]=[h][p]
// ---------------------------------------------------------------------------
__global__ __launch_bounds__(128)
void aw_softmax(float* __restrict__ aw)
{
    const int bq = blockIdx.x;
    const int tid = threadIdx.x;
    const float v = aw[(size_t)bq*128 + tid];
    float m = v;
#pragma unroll
    for (int off = 8; off; off >>= 1) m = fmaxf(m, __shfl_xor(m, off, 16));
    const float e = __expf(v - m);
    float s = e;
#pragma unroll
    for (int off = 8; off; off >>= 1) s += __shfl_xor(s, off, 16);
    aw[(size_t)bq*128 + tid] = e / s;
}

// ---------------------------------------------------------------------------
// MS-deformable attention gather. One block per (b,q); 256 thr = 8 heads x 32 d.
// ---------------------------------------------------------------------------
__global__ __launch_bounds__(256)
void deform_attn(const float* __restrict__ value, const float* __restrict__ refp,
                 const float* __restrict__ so, const float* __restrict__ aw,
                 float* __restrict__ outp)
{
    const int bq = blockIdx.x;
    const int b  = bq / LQ;
    const int tid = threadIdx.x;
    __shared__ int   s_idx[128][4];
    __shared__ float s_w[128][4];
    if (tid < 128) {
        const int hp = tid;
        const int p  = hp & 15;
        const int lvl = p >> 2;
        const float Wl = (lvl == 0) ? 80.f : (lvl == 1) ? 40.f : (lvl == 2) ? 20.f : 10.f;
        const float Hl = Wl;
        const int off  = (lvl == 0) ? 0 : (lvl == 1) ? 6400 : (lvl == 2) ? 8000 : 8400;
        const float cx = refp[bq*4+0], cy = refp[bq*4+1];
        const float rw = refp[bq*4+2], rh = refp[bq*4+3];
        const float lx = cx + so[(size_t)bq*256 + hp*2 + 0] * rw * 0.125f;
        const float ly = cy + so[(size_t)bq*256 + hp*2 + 1] * rh * 0.125f;
        const float x = lx * Wl - 0.5f;
        const float y = ly * Hl - 0.5f;
        const float x0 = floorf(x), y0 = floorf(y);
        const float wx1 = x - x0, wx0 = 1.f - wx1;
        const float wy1 = y - y0, wy0 = 1.f - wy1;
        const float a = aw[(size_t)bq*128 + hp];
        const float xs[2]  = {x0, x0 + 1.f}, ys[2]  = {y0, y0 + 1.f};
        const float wxs[2] = {wx0, wx1},     wys[2] = {wy0, wy1};
#pragma unroll
        for (int cyi = 0; cyi < 2; ++cyi)
#pragma unroll
            for (int cxi = 0; cxi < 2; ++cxi) {
                const float xi = xs[cxi], yi = ys[cyi];
                const bool valid = (xi >= 0.f) && (xi <= Wl - 1.f) &&
                                   (yi >= 0.f) && (yi <= Hl - 1.f);
                const float xc = fminf(fmaxf(xi, 0.f), Wl - 1.f);
                const float yc = fminf(fmaxf(yi, 0.f), Hl - 1.f);
                const int c = cyi*2 + cxi;
                s_idx[hp][c] = (int)(yc*Wl + xc) + off;
                s_w[hp][c]   = valid ? (wxs[cxi]*wys[cyi]*a) : 0.f;
            }
    }
    __syncthreads();
    const int h = tid >> 5, d = tid & 31;
    const int col = h*32 + d;
    const float* vb = value + (size_t)b * LEN_V * 256;
    float acc = 0.f;
#pragma unroll
    for (int p = 0; p < 16; ++p) {
        const int hp = (h << 4) | p;
#pragma unroll
        for (int c = 0; c < 4; ++c)
            acc += s_w[hp][c] * vb[(size_t)s_idx[hp][c]*256 + col];
    }
    outp[(size_t)bq*256 + col] = acc;
}

// cat = [t | t2] per row
__global__ __launch_bounds__(512)
void cat2(const float* __restrict__ t, const float* __restrict__ t2,
          float* __restrict__ catb)
{
    const int row = blockIdx.x, dd = threadIdx.x;
    catb[(size_t)row*512 + dd] = (dd < 256) ? t[(size_t)row*256 + dd]
                                            : t2[(size_t)row*256 + dd - 256];
}

// ---------------------------------------------------------------------------
extern "C" void kernel_launch(void* const* d_in, const int* in_sizes, int n_in,
                              void* d_out, int out_size, void* d_ws, size_t ws_size,
                              hipStream_t stream)
{
    (void)in_sizes; (void)n_in; (void)out_size; (void)ws_size;
    const float* target = (const float*)d_in[0];
    const float* refp   = (const float*)d_in[1];
    const float* value  = (const float*)d_in[2];
    const float* qpos   = (const float*)d_in[3];
    const float* Wqkv   = (const float*)d_in[4];
    const float* bqkv   = (const float*)d_in[5];
    const float* Wo     = (const float*)d_in[6];
    const float* bo     = (const float*)d_in[7];
    const float* n1g    = (const float*)d_in[8];
    const float* n1b    = (const float*)d_in[9];
    const float* soW    = (const float*)d_in[10];
    const float* sob    = (const float*)d_in[11];
    const float* awW    = (const float*)d_in[12];
    const float* awb    = (const float*)d_in[13];
    const float* gW     = (const float*)d_in[14];
    const float* gb     = (const float*)d_in[15];
    const float* gng    = (const float*)d_in[16];
    const float* gnb    = (const float*)d_in[17];
    const float* l1W    = (const float*)d_in[18];
    const float* l1b    = (const float*)d_in[19];
    const float* l2W    = (const float*)d_in[20];
    const float* l2b    = (const float*)d_in[21];
    const float* n3g    = (const float*)d_in[22];
    const float* n3b    = (const float*)d_in[23];

    float* p = (float*)d_ws;
    float* t_buf = p;  p += (size_t)ROWS*D;
    float* q_buf = p;  p += (size_t)ROWS*D;
    float* qkv   = p;                               // ROWS*768
    float* o_buf = qkv + (size_t)ROWS*768;          // ROWS*256
    float* hid   = qkv;                             // aliases qkv+o (ROWS*1024)
    p += (size_t)ROWS*(768 + 256);
    float* t2    = p;  p += (size_t)ROWS*D;
    float* so_b  = p;  p += (size_t)ROWS*D;
    float* aw_b  = p;  p += (size_t)ROWS*128;
    float* cat_b = p;  p += (size_t)ROWS*512;
    float* gates = p;  p += (size_t)ROWS*512;

    hipMemcpyAsync(t_buf, target, (size_t)ROWS*D*sizeof(float),
                   hipMemcpyDeviceToDevice, stream);

    for (int i = 0; i < 6; ++i) {
        const float* Wqkv_i = Wqkv + (size_t)i*768*256;
        const float* bqkv_i = bqkv + (size_t)i*768;
        const float* Wo_i   = Wo   + (size_t)i*256*256;
        const float* bo_i   = bo   + (size_t)i*256;
        const float* n1g_i  = n1g  + (size_t)i*256;
        const float* n1b_i  = n1b  + (size_t)i*256;
        const float* soW_i  = soW  + (size_t)i*256*256;
        const float* sob_i  = sob  + (size_t)i*256;
        const float* awW_i  = awW  + (size_t)i*128*256;
        const float* awb_i  = awb  + (size_t)i*128;
        const float* gW_i   = gW   + (size_t)i*512*512;
        const float* gb_i   = gb   + (size_t)i*512;
        const float* gng_i  = gng  + (size_t)i*256;
        const float* gnb_i  = gnb  + (size_t)i*256;
        const float* l1W_i  = l1W  + (size_t)i*1024*256;
        const float* l1b_i  = l1b  + (size_t)i*1024;
        const float* l2W_i  = l2W  + (size_t)i*256*1024;
        const float* l2b_i  = l2b  + (size_t)i*256;
        const float* n3g_i  = n3g  + (size_t)i*256;
        const float* n3b_i  = n3b  + (size_t)i*256;

        // ---- MHA ----
        add_pos<<<ROWS, 256, 0, stream>>>(t_buf, qpos, q_buf);
        gemm_tn<0><<<dim3(75, 8), 256, 0, stream>>>(q_buf, 256, Wqkv_i,          bqkv_i,       qkv, 768, 0,   256);
        gemm_tn<0><<<dim3(75, 4), 256, 0, stream>>>(t_buf, 256, Wqkv_i + 512*256, bqkv_i + 512, qkv, 768, 512, 256);
        mha_block<<<BS*NH*4, 256, 0, stream>>>(qkv, o_buf);
        gemm_tn<0><<<dim3(75, 4), 256, 0, stream>>>(o_buf, 256, Wo_i, bo_i, t2, 256, 0, 256);
        ln_res_pos<<<ROWS, 256, 0, stream>>>(t_buf, t2, n1g_i, n1b_i, qpos, t_buf, q_buf);

        // ---- deformable attention ----
        gemm_tn<0><<<dim3(75, 4), 256, 0, stream>>>(q_buf, 256, soW_i, sob_i, so_b, 256, 0, 256);
        gemm_tn<0><<<dim3(75, 2), 256, 0, stream>>>(q_buf, 256, awW_i, awb_i, aw_b, 128, 0, 256);
        aw_softmax<<<ROWS, 128, 0, stream>>>(aw_b);
        deform_attn<<<ROWS, 256, 0, stream>>>(value, refp, so_b, aw_b, t2);

        // ---- gating ----
        cat2<<<ROWS, 512, 0, stream>>>(t_buf, t2, cat_b);
        gemm_tn<2><<<dim3(75, 8), 256, 0, stream>>>(cat_b, 512, gW_i, gb_i, gates, 512, 0, 512);
        gate_ln<<<ROWS, 256, 0, stream>>>(t_buf, t2, gates, gng_i, gnb_i, t_buf);

        // ---- FFN ----
        gemm_tn<1><<<dim3(75, 16), 256, 0, stream>>>(t_buf, 256, l1W_i, l1b_i, hid, 1024, 0, 256);
        gemm_tn<0><<<dim3(75, 4), 256, 0, stream>>>(hid, 1024, l2W_i, l2b_i, t2, 256, 0, 1024);
        ln_clip<<<ROWS, 256, 0, stream>>>(t_buf, t2, n3g_i, n3b_i,
                                          (i == 5) ? (float*)d_out : t_buf);
    }
}

// Round 3
// 1396.187 us; speedup vs baseline: 3.7281x; 1.6834x over previous
//
#include <hip/hip_runtime.h>

#define BS 16
#define LQ 300
#define D 256
#define NH 8
#define HD 32
#define DFF 1024
#define ROWS (BS*LQ)    // 4800
#define LEN_V 8500

typedef __attribute__((ext_vector_type(8))) short short8;
typedef __attribute__((ext_vector_type(4))) float f32x4;

// bf16 round-to-nearest-even (low 16 bits)
__device__ __forceinline__ uint32_t bf16r(float x)
{
    const uint32_t u = __float_as_uint(x);
    return (u + 0x7fffu + ((u >> 16) & 1u)) >> 16;
}
__device__ __forceinline__ float lof(uint32_t p) { return __uint_as_float(p << 16); }
__device__ __forceinline__ float hif(uint32_t p) { return __uint_as_float(p & 0xffff0000u); }

// ---------------------------------------------------------------------------
// bf16 MFMA GEMM: C[m, coff+n] = act( sum_k A[m,k] * W[n,k] + bias[n] )
// A,W are f32 in global; converted to bf16 while staging into XOR-swizzled LDS.
// Tile 64x64, BK=64, 256 thr = 4 waves, each wave a 32x32 sub-tile (2x2 frags
// of 16x16x32). Optional second A source (A2) for k>=ksplit (concat fusion).
// ACT: 0=none, 1=relu, 2=sigmoid
// ---------------------------------------------------------------------------
template<int ACT>
__global__ __launch_bounds__(256)
void gemm_mfma(const float* __restrict__ A, int lda,
               const float* __restrict__ A2, int lda2, int ksplit,
               const float* __restrict__ W,
               const float* __restrict__ bias,
               float* __restrict__ C, int ldc, int coff,
               int K)
{
    __shared__ __align__(16) unsigned short As[64*64];   // [row][slot^], 128B rows
    __shared__ __align__(16) unsigned short Bs[64*64];
    const int tid  = threadIdx.x;
    const int bm   = blockIdx.x, bn = blockIdx.y;
    const int lane = tid & 63;
    const int w    = tid >> 6;
    const int wm   = (w >> 1) * 32, wn = (w & 1) * 32;
    const int fr   = lane & 15;     // fragment row/col
    const int fq   = lane >> 4;     // k-quad

    const int srow = tid >> 2;      // staging row 0..63
    const int sg   = tid & 3;       // staging group sub-index

    f32x4 acc[2][2] = {};

    for (int k0 = 0; k0 < K; k0 += 64) {
        // ---- global f32 loads (8 floats per thread per pass, 2 passes) ----
        float4 a0[2], a1[2], w0[2], w1[2];
#pragma unroll
        for (int p = 0; p < 2; ++p) {
            const int grp = sg + 4*p;         // 16B-slot 0..7
            const int kg  = k0 + grp*8;
            const float* Asrc = (A2 != nullptr && kg >= ksplit)
                ? (A2 + (size_t)(bm*64 + srow)*lda2 + (kg - ksplit))
                : (A  + (size_t)(bm*64 + srow)*lda  + kg);
            a0[p] = *reinterpret_cast<const float4*>(Asrc);
            a1[p] = *reinterpret_cast<const float4*>(Asrc + 4);
            const float* Wsrc = W + (size_t)(bn*64 + srow)*K + kg;
            w0[p] = *reinterpret_cast<const float4*>(Wsrc);
            w1[p] = *reinterpret_cast<const float4*>(Wsrc + 4);
        }
        __syncthreads();
#pragma unroll
        for (int p = 0; p < 2; ++p) {
            const int grp  = sg + 4*p;
            const int slot = grp ^ (srow & 7);
            uint32_t pk[4];
            pk[0] = bf16r(a0[p].x) | (bf16r(a0[p].y) << 16);
            pk[1] = bf16r(a0[p].z) | (bf16r(a0[p].w) << 16);
            pk[2] = bf16r(a1[p].x) | (bf16r(a1[p].y) << 16);
            pk[3] = bf16r(a1[p].z) | (bf16r(a1[p].w) << 16);
            *reinterpret_cast<uint4*>(&As[srow*64 + slot*8]) =
                make_uint4(pk[0], pk[1], pk[2], pk[3]);
            pk[0] = bf16r(w0[p].x) | (bf16r(w0[p].y) << 16);
            pk[1] = bf16r(w0[p].z) | (bf16r(w0[p].w) << 16);
            pk[2] = bf16r(w1[p].x) | (bf16r(w1[p].y) << 16);
            pk[3] = bf16r(w1[p].z) | (bf16r(w1[p].w) << 16);
            *reinterpret_cast<uint4*>(&Bs[srow*64 + slot*8]) =
                make_uint4(pk[0], pk[1], pk[2], pk[3]);
        }
        __syncthreads();
        // ---- compute: 2 k-subs x (2m x 2n) MFMA ----
#pragma unroll
        for (int ks = 0; ks < 2; ++ks) {
            short8 af[2], bf[2];
#pragma unroll
            for (int fm = 0; fm < 2; ++fm) {
                const int row = wm + fm*16 + fr;
                const int slot = (ks*4 + fq) ^ (row & 7);
                af[fm] = *reinterpret_cast<const short8*>(&As[row*64 + slot*8]);
            }
#pragma unroll
            for (int fn = 0; fn < 2; ++fn) {
                const int row = wn + fn*16 + fr;
                const int slot = (ks*4 + fq) ^ (row & 7);
                bf[fn] = *reinterpret_cast<const short8*>(&Bs[row*64 + slot*8]);
            }
#pragma unroll
            for (int fm = 0; fm < 2; ++fm)
#pragma unroll
                for (int fn = 0; fn < 2; ++fn)
                    acc[fm][fn] = __builtin_amdgcn_mfma_f32_16x16x32_bf16(
                        af[fm], bf[fn], acc[fm][fn], 0, 0, 0);
        }
    }

    // ---- epilogue: C[row][col], col=lane&15, row=fq*4+r ----
#pragma unroll
    for (int fm = 0; fm < 2; ++fm)
#pragma unroll
        for (int fn = 0; fn < 2; ++fn) {
            const int col = bn*64 + wn + fn*16 + fr;
            const float bia = bias[col];
#pragma unroll
            for (int r = 0; r < 4; ++r) {
                const int row = bm*64 + wm + fm*16 + fq*4 + r;
                float v = acc[fm][fn][r] + bia;
                if (ACT == 1) v = fmaxf(v, 0.f);
                if (ACT == 2) v = 1.f / (1.f + __expf(-v));
                C[(size_t)row*ldc + coff + col] = v;
            }
        }
}

// ---------------------------------------------------------------------------
__global__ __launch_bounds__(256)
void add_pos(const float* __restrict__ t, const float* __restrict__ pos,
             float* __restrict__ q)
{
    const size_t idx = (size_t)blockIdx.x*256 + threadIdx.x;
    q[idx] = t[idx] + pos[idx];
}

// ---------------------------------------------------------------------------
// Fused MHA, keys-across-lanes. One block per (b, h, quarter-of-queries).
// ---------------------------------------------------------------------------
__global__ __launch_bounds__(256)
void mha_block(const float* __restrict__ qkv, float* __restrict__ o)
{
    const int blk = blockIdx.x;          // ((b*8+h)*4 + quarter)
    const int quarter = blk & 3;
    const int bh = blk >> 2;
    const int b = bh >> 3, h = bh & 7;
    const int tid = threadIdx.x;
    const int lane = tid & 63;
    const int w = tid >> 6;

    __shared__ uint32_t Kp[16][320];     // [d-pair][key], pad cols 300..319 = 0
    __shared__ uint32_t Vp[150][32];     // [key-pair][d]
    __shared__ float    ws[4][304];      // per-wave softmax weights
    const float* base = qkv + (size_t)b * LQ * 768;
    const int hc = h * 32;

    for (int idx = tid; idx < 300*16; idx += 256) {
        const int j = idx >> 4, d2 = idx & 15;
        const float2 kv = *reinterpret_cast<const float2*>(base + (size_t)j*768 + 256 + hc + 2*d2);
        Kp[d2][j] = (bf16r(kv.y) << 16) | bf16r(kv.x);
    }
    for (int idx = tid; idx < 16*20; idx += 256)
        Kp[idx/20][300 + idx%20] = 0;
    for (int idx = tid; idx < 150*32; idx += 256) {
        const int jp = idx >> 5, d = idx & 31;
        const float lo = base[(size_t)(2*jp  )*768 + 512 + hc + d];
        const float hi = base[(size_t)(2*jp+1)*768 + 512 + hc + d];
        Vp[jp][d] = (bf16r(hi) << 16) | bf16r(lo);
    }
    __syncthreads();

    const float scale = 0.17677669529663687f;   // 1/sqrt(32)
    const int qbase = quarter * 75;
    for (int il = w; il < 75; il += 4) {
        const int iq = qbase + il;
        const float2* qrow = reinterpret_cast<const float2*>(base + (size_t)iq*768 + hc);

        float s0=0.f, s1=0.f, s2=0.f, s3=0.f, s4=0.f;
#pragma unroll
        for (int d2 = 0; d2 < 16; ++d2) {
            const float2 q2 = qrow[d2];
            uint32_t k;
            k = Kp[d2][lane      ]; s0 += lof(k)*q2.x + hif(k)*q2.y;
            k = Kp[d2][lane +  64]; s1 += lof(k)*q2.x + hif(k)*q2.y;
            k = Kp[d2][lane + 128]; s2 += lof(k)*q2.x + hif(k)*q2.y;
            k = Kp[d2][lane + 192]; s3 += lof(k)*q2.x + hif(k)*q2.y;
            k = Kp[d2][lane + 256]; s4 += lof(k)*q2.x + hif(k)*q2.y;
        }
        s0 *= scale; s1 *= scale; s2 *= scale; s3 *= scale;
        s4 = (lane < 44) ? s4*scale : -3e38f;

        float m = fmaxf(fmaxf(fmaxf(s0,s1), fmaxf(s2,s3)), s4);
#pragma unroll
        for (int off = 32; off; off >>= 1) m = fmaxf(m, __shfl_xor(m, off));
        const float e0 = __expf(s0-m), e1 = __expf(s1-m), e2 = __expf(s2-m), e3 = __expf(s3-m);
        const float e4 = (lane < 44) ? __expf(s4-m) : 0.f;
        float sum = e0+e1+e2+e3+e4;
#pragma unroll
        for (int off = 32; off; off >>= 1) sum += __shfl_xor(sum, off);
        const float inv = 1.f / sum;
        ws[w][lane      ] = e0;
        ws[w][lane +  64] = e1;
        ws[w][lane + 128] = e2;
        ws[w][lane + 192] = e3;
        if (lane < 44) ws[w][lane + 256] = e4;

        const int half = lane >> 5, d = lane & 31;
        float acc = 0.f;
#pragma unroll 5
        for (int jp = half*75; jp < half*75 + 75; ++jp) {
            const float2 w2 = *reinterpret_cast<const float2*>(&ws[w][2*jp]);
            const uint32_t v2 = Vp[jp][d];
            acc += lof(v2)*w2.x + hif(v2)*w2.y;
        }
        acc += __shfl_down(acc, 32);
        if (lane < 32)
            o[((size_t)(b*LQ + iq))*256 + hc + d] = acc * inv;
    }
}

// ---------------------------------------------------------------------------
__device__ __forceinline__ float blk_sum(float v, float* red)
{
#pragma unroll
    for (int off = 32; off; off >>= 1) v += __shfl_down(v, off, 64);
    const int lane = threadIdx.x & 63, w = threadIdx.x >> 6;
    if (lane == 0) red[w] = v;
    __syncthreads();
    const float s = red[0] + red[1] + red[2] + red[3];
    __syncthreads();
    return s;
}

__global__ __launch_bounds__(256)
void ln_res_pos(const float* __restrict__ t, const float* __restrict__ t2,
                const float* __restrict__ g, const float* __restrict__ bb,
                const float* __restrict__ pos,
                float* __restrict__ t_out, float* __restrict__ q_out)
{
    __shared__ float red[4];
    const size_t idx = (size_t)blockIdx.x*256 + threadIdx.x;
    const float x = t[idx] + t2[idx];
    const float mean = blk_sum(x, red) * (1.f/256.f);
    const float c = x - mean;
    const float var = blk_sum(c*c, red) * (1.f/256.f);
    const float y = c * rsqrtf(var + 1e-5f) * g[threadIdx.x] + bb[threadIdx.x];
    t_out[idx] = y;
    q_out[idx] = y + pos[idx];
}

__global__ __launch_bounds__(256)
void gate_ln(const float* __restrict__ t, const float* __restrict__ t2,
             const float* __restrict__ gates,
             const float* __restrict__ g, const float* __restrict__ bb,
             float* __restrict__ t_out)
{
    __shared__ float red[4];
    const int row = blockIdx.x, dd = threadIdx.x;
    const size_t idx = (size_t)row*256 + dd;
    const float g1 = gates[(size_t)row*512 + dd];
    const float g2 = gates[(size_t)row*512 + 256 + dd];
    const float x = g1 * t[idx] + g2 * t2[idx];
    const float mean = blk_sum(x, red) * (1.f/256.f);
    const float c = x - mean;
    const float var = blk_sum(c*c, red) * (1.f/256.f);
    t_out[idx] = c * rsqrtf(var + 1e-5f) * g[dd] + bb[dd];
}

__global__ __launch_bounds__(256)
void ln_clip(const float* __restrict__ t, const float* __restrict__ t2,
             const float* __restrict__ g, const float* __restrict__ bb,
             float* __restrict__ outp)
{
    __shared__ float red[4];
    const size_t idx = (size_t)blockIdx.x*256 + threadIdx.x;
    float x = t[idx] + t2[idx];
    x = fminf(fmaxf(x, -65504.f), 65504.f);
    const float mean = blk_sum(x, red) * (1.f/256.f);
    const float c = x - mean;
    const float var = blk_sum(c*c, red) * (1.f/256.f);
    outp[idx] = c * rsqrtf(var + 1e-5f) * g[threadIdx.x] + bb[threadIdx.x];
}

// ---------------------------------------------------------------------------
__global__ __launch_bounds__(128)
void aw_softmax(float* __restrict__ aw)
{
    const int bq = blockIdx.x;
    const int tid = threadIdx.x;
    const float v = aw[(size_t)bq*128 + tid];
    float m = v;
#pragma unroll
    for (int off = 8; off; off >>= 1) m = fmaxf(m, __shfl_xor(m, off, 16));
    const float e = __expf(v - m);
    float s = e;
#pragma unroll
    for (int off = 8; off; off >>= 1) s += __shfl_xor(s, off, 16);
    aw[(size_t)bq*128 + tid] = e / s;
}

// ---------------------------------------------------------------------------
__global__ __launch_bounds__(256)
void deform_attn(const float* __restrict__ value, const float* __restrict__ refp,
                 const float* __restrict__ so, const float* __restrict__ aw,
                 float* __restrict__ outp)
{
    const int bq = blockIdx.x;
    const int b  = bq / LQ;
    const int tid = threadIdx.x;
    __shared__ int   s_idx[128][4];
    __shared__ float s_w[128][4];
    if (tid < 128) {
        const int hp = tid;
        const int p  = hp & 15;
        const int lvl = p >> 2;
        const float Wl = (lvl == 0) ? 80.f : (lvl == 1) ? 40.f : (lvl == 2) ? 20.f : 10.f;
        const float Hl = Wl;
        const int off  = (lvl == 0) ? 0 : (lvl == 1) ? 6400 : (lvl == 2) ? 8000 : 8400;
        const float cx = refp[bq*4+0], cy = refp[bq*4+1];
        const float rw = refp[bq*4+2], rh = refp[bq*4+3];
        const float lx = cx + so[(size_t)bq*256 + hp*2 + 0] * rw * 0.125f;
        const float ly = cy + so[(size_t)bq*256 + hp*2 + 1] * rh * 0.125f;
        const float x = lx * Wl - 0.5f;
        const float y = ly * Hl - 0.5f;
        const float x0 = floorf(x), y0 = floorf(y);
        const float wx1 = x - x0, wx0 = 1.f - wx1;
        const float wy1 = y - y0, wy0 = 1.f - wy1;
        const float a = aw[(size_t)bq*128 + hp];
        const float xs[2]  = {x0, x0 + 1.f}, ys[2]  = {y0, y0 + 1.f};
        const float wxs[2] = {wx0, wx1},     wys[2] = {wy0, wy1};
#pragma unroll
        for (int cyi = 0; cyi < 2; ++cyi)
#pragma unroll
            for (int cxi = 0; cxi < 2; ++cxi) {
                const float xi = xs[cxi], yi = ys[cyi];
                const bool valid = (xi >= 0.f) && (xi <= Wl - 1.f) &&
                                   (yi >= 0.f) && (yi <= Hl - 1.f);
                const float xc = fminf(fmaxf(xi, 0.f), Wl - 1.f);
                const float yc = fminf(fmaxf(yi, 0.f), Hl - 1.f);
                const int c = cyi*2 + cxi;
                s_idx[hp][c] = (int)(yc*Wl + xc) + off;
                s_w[hp][c]   = valid ? (wxs[cxi]*wys[cyi]*a) : 0.f;
            }
    }
    __syncthreads();
    const int h = tid >> 5, d = tid & 31;
    const int col = h*32 + d;
    const float* vb = value + (size_t)b * LEN_V * 256;
    float acc = 0.f;
#pragma unroll
    for (int p = 0; p < 16; ++p) {
        const int hp = (h << 4) | p;
#pragma unroll
        for (int c = 0; c < 4; ++c)
            acc += s_w[hp][c] * vb[(size_t)s_idx[hp][c]*256 + col];
    }
    outp[(size_t)bq*256 + col] = acc;
}

// ---------------------------------------------------------------------------
extern "C" void kernel_launch(void* const* d_in, const int* in_sizes, int n_in,
                              void* d_out, int out_size, void* d_ws, size_t ws_size,
                              hipStream_t stream)
{
    (void)in_sizes; (void)n_in; (void)out_size; (void)ws_size;
    const float* target = (const float*)d_in[0];
    const float* refp   = (const float*)d_in[1];
    const float* value  = (const float*)d_in[2];
    const float* qpos   = (const float*)d_in[3];
    const float* Wqkv   = (const float*)d_in[4];
    const float* bqkv   = (const float*)d_in[5];
    const float* Wo     = (const float*)d_in[6];
    const float* bo     = (const float*)d_in[7];
    const float* n1g    = (const float*)d_in[8];
    const float* n1b    = (const float*)d_in[9];
    const float* soW    = (const float*)d_in[10];
    const float* sob    = (const float*)d_in[11];
    const float* awW    = (const float*)d_in[12];
    const float* awb    = (const float*)d_in[13];
    const float* gW     = (const float*)d_in[14];
    const float* gb     = (const float*)d_in[15];
    const float* gng    = (const float*)d_in[16];
    const float* gnb    = (const float*)d_in[17];
    const float* l1W    = (const float*)d_in[18];
    const float* l1b    = (const float*)d_in[19];
    const float* l2W    = (const float*)d_in[20];
    const float* l2b    = (const float*)d_in[21];
    const float* n3g    = (const float*)d_in[22];
    const float* n3b    = (const float*)d_in[23];

    float* p = (float*)d_ws;
    float* t_buf = p;  p += (size_t)ROWS*D;
    float* q_buf = p;  p += (size_t)ROWS*D;
    float* qkv   = p;                               // ROWS*768
    float* o_buf = qkv + (size_t)ROWS*768;          // ROWS*256
    float* hid   = qkv;                             // aliases qkv+o (ROWS*1024)
    p += (size_t)ROWS*(768 + 256);
    float* t2    = p;  p += (size_t)ROWS*D;
    float* so_b  = p;  p += (size_t)ROWS*D;
    float* aw_b  = p;  p += (size_t)ROWS*128;
    float* gates = p;  p += (size_t)ROWS*512;

    hipMemcpyAsync(t_buf, target, (size_t)ROWS*D*sizeof(float),
                   hipMemcpyDeviceToDevice, stream);

    for (int i = 0; i < 6; ++i) {
        const float* Wqkv_i = Wqkv + (size_t)i*768*256;
        const float* bqkv_i = bqkv + (size_t)i*768;
        const float* Wo_i   = Wo   + (size_t)i*256*256;
        const float* bo_i   = bo   + (size_t)i*256;
        const float* n1g_i  = n1g  + (size_t)i*256;
        const float* n1b_i  = n1b  + (size_t)i*256;
        const float* soW_i  = soW  + (size_t)i*256*256;
        const float* sob_i  = sob  + (size_t)i*256;
        const float* awW_i  = awW  + (size_t)i*128*256;
        const float* awb_i  = awb  + (size_t)i*128;
        const float* gW_i   = gW   + (size_t)i*512*512;
        const float* gb_i   = gb   + (size_t)i*512;
        const float* gng_i  = gng  + (size_t)i*256;
        const float* gnb_i  = gnb  + (size_t)i*256;
        const float* l1W_i  = l1W  + (size_t)i*1024*256;
        const float* l1b_i  = l1b  + (size_t)i*1024;
        const float* l2W_i  = l2W  + (size_t)i*256*1024;
        const float* l2b_i  = l2b  + (size_t)i*256;
        const float* n3g_i  = n3g  + (size_t)i*256;
        const float* n3b_i  = n3b  + (size_t)i*256;

        // ---- MHA ----
        add_pos<<<ROWS, 256, 0, stream>>>(t_buf, qpos, q_buf);
        gemm_mfma<0><<<dim3(75, 8), 256, 0, stream>>>(q_buf, 256, nullptr, 0, 0,
            Wqkv_i, bqkv_i, qkv, 768, 0, 256);
        gemm_mfma<0><<<dim3(75, 4), 256, 0, stream>>>(t_buf, 256, nullptr, 0, 0,
            Wqkv_i + 512*256, bqkv_i + 512, qkv, 768, 512, 256);
        mha_block<<<BS*NH*4, 256, 0, stream>>>(qkv, o_buf);
        gemm_mfma<0><<<dim3(75, 4), 256, 0, stream>>>(o_buf, 256, nullptr, 0, 0,
            Wo_i, bo_i, t2, 256, 0, 256);
        ln_res_pos<<<ROWS, 256, 0, stream>>>(t_buf, t2, n1g_i, n1b_i, qpos, t_buf, q_buf);

        // ---- deformable attention ----
        gemm_mfma<0><<<dim3(75, 4), 256, 0, stream>>>(q_buf, 256, nullptr, 0, 0,
            soW_i, sob_i, so_b, 256, 0, 256);
        gemm_mfma<0><<<dim3(75, 2), 256, 0, stream>>>(q_buf, 256, nullptr, 0, 0,
            awW_i, awb_i, aw_b, 128, 0, 256);
        aw_softmax<<<ROWS, 128, 0, stream>>>(aw_b);
        deform_attn<<<ROWS, 256, 0, stream>>>(value, refp, so_b, aw_b, t2);

        // ---- gating (concat fused into GEMM A-staging) ----
        gemm_mfma<2><<<dim3(75, 8), 256, 0, stream>>>(t_buf, 256, t2, 256, 256,
            gW_i, gb_i, gates, 512, 0, 512);
        gate_ln<<<ROWS, 256, 0, stream>>>(t_buf, t2, gates, gng_i, gnb_i, t_buf);

        // ---- FFN ----
        gemm_mfma<1><<<dim3(75, 16), 256, 0, stream>>>(t_buf, 256, nullptr, 0, 0,
            l1W_i, l1b_i, hid, 1024, 0, 256);
        gemm_mfma<0><<<dim3(75, 4), 256, 0, stream>>>(hid, 1024, nullptr, 0, 0,
            l2W_i, l2b_i, t2, 256, 0, 1024);
        ln_clip<<<ROWS, 256, 0, stream>>>(t_buf, t2, n3g_i, n3b_i,
                                          (i == 5) ? (float*)d_out : t_buf);
    }
}